// Round 13
// baseline (110.630 us; speedup 1.0000x reference)
//
#include <hip/hip_runtime.h>

#define EMB 64
#define HEADS 8
#define SEQ 2048
#define LSF 68

typedef short short8 __attribute__((ext_vector_type(8)));
typedef float f32x4 __attribute__((ext_vector_type(4)));
typedef unsigned int u32;

__device__ __forceinline__ float4 ld4(const float* p) { return *(const float4*)p; }
__device__ __forceinline__ unsigned short f2bf(float f) {
  union { float f; unsigned u; } x; x.f = f;
  return (unsigned short)((x.u + 0x7fffu + ((x.u >> 16) & 1u)) >> 16);
}
__device__ __forceinline__ float bf2f(unsigned short s) {
  union { unsigned u; float f; } x; x.u = ((unsigned)s) << 16;
  return x.f;
}
__device__ __forceinline__ float bits2f(u32 u) {
  union { u32 u; float f; } x; x.u = u;
  return x.f;
}
__device__ __forceinline__ u32 cvtpk(float lo, float hi) {
  u32 r;
  asm("v_cvt_pk_bf16_f32 %0, %1, %2" : "=v"(r) : "v"(lo), "v"(hi));
  return r;
}
__device__ __forceinline__ float vexp2(float x) {
  float r;
  asm("v_exp_f32 %0, %1" : "=v"(r) : "v"(x));
  return r;
}
__device__ __forceinline__ void gload16(const void* g, void* l) {
  __builtin_amdgcn_global_load_lds((const __attribute__((address_space(1))) unsigned int*)g,
                                   (__attribute__((address_space(3))) unsigned int*)l, 16, 0, 0);
}

#define LOG2E 1.4426950408889634f
#define NC0  (-5.770780163555854f)   /* -4 * log2(e) */

// ---- split: x,y -> exact hi/lo bf16 planes; Wk/Wv/Wq -> transposed hi/lo planes ----
__global__ __launch_bounds__(256) void split_kernel(
    const float* __restrict__ x, const float* __restrict__ y,
    const float* __restrict__ Wk, const float* __restrict__ Wq, const float* __restrict__ Wv,
    unsigned short* __restrict__ xhi, unsigned short* __restrict__ xlo,
    unsigned short* __restrict__ yhi, unsigned short* __restrict__ ylo,
    unsigned short* __restrict__ WT)
{
  const int gid = blockIdx.x * 256 + threadIdx.x;
  if (blockIdx.x < 1024) {
    const int i4 = gid & 131071;
    const bool isY = gid >= 131072;
    const float4 v = ld4((isY ? y : x) + (size_t)i4 * 4);
    ushort4 hi, lo;
    hi.x = f2bf(v.x); lo.x = f2bf(v.x - bf2f(hi.x));
    hi.y = f2bf(v.y); lo.y = f2bf(v.y - bf2f(hi.y));
    hi.z = f2bf(v.z); lo.z = f2bf(v.z - bf2f(hi.z));
    hi.w = f2bf(v.w); lo.w = f2bf(v.w - bf2f(hi.w));
    *(ushort4*)&(isY ? yhi : xhi)[(size_t)i4 * 4] = hi;
    *(ushort4*)&(isY ? ylo : xlo)[(size_t)i4 * 4] = lo;
  } else {
    // WT[z][plane][n=512][k=64]; z: 0=Wk 1=Wv 2=Wq
    const int e = gid - 1024 * 256;        // 0..98303
    if (e >= 98304) return;
    const int z = e >> 15;
    const int nk = e & 32767;
    const int n = nk >> 6, k = nk & 63;
    const float* __restrict__ W = (z == 0) ? Wk : (z == 1) ? Wv : Wq;
    const float wv = W[(size_t)k * (EMB * HEADS) + n];
    const unsigned short hi = f2bf(wv);
    const unsigned short lo = f2bf(wv - bf2f(hi));
    WT[(size_t)z * 65536 + nk] = hi;
    WT[(size_t)z * 65536 + 32768 + nk] = lo;
  }
}

// ---- projections via MFMA (R12-proven) + LDS-staged coalesced maskpack + WuT ----
__global__ __launch_bounds__(256) void projmfma_kernel(
    const unsigned short* __restrict__ xhi, const unsigned short* __restrict__ xlo,
    const unsigned short* __restrict__ yhi, const unsigned short* __restrict__ ylo,
    const unsigned short* __restrict__ WT, const int* __restrict__ mask,
    const float* __restrict__ Wu,
    unsigned short* __restrict__ Kbuf, unsigned short* __restrict__ Qbuf,
    unsigned short* __restrict__ VbufT, u32* __restrict__ pmask,
    unsigned short* __restrict__ WuThi, unsigned short* __restrict__ WuTlo)
{
  __shared__ int Ms[64][LSF];      // z=3 mask tile (z=0..2 paths don't use LDS)
  const int t = threadIdx.x;
  const int z = blockIdx.z;        // 0:K 1:V^T 2:Q 3:maskpack(+WuT)

  if (z == 3) {
    const int bid = blockIdx.x * 8 + blockIdx.y;     // 0..1023 = qblk*32 + kt
    const int qblk = bid >> 5, kt = bid & 31;
    // stage 64x64 int mask tile, fully coalesced
    #pragma unroll
    for (int j = 0; j < 4; ++j) {
      const int idx = t + j * 256;                   // 0..1023 int4-groups
      const int row = idx >> 4, col4 = (idx & 15) << 2;
      *(int4*)&Ms[row][col4] =
          *(const int4*)&mask[(size_t)(qblk*64 + row) * SEQ + kt*64 + col4];
    }
    __syncthreads();
    // emit Pmask words in the R8-proven layout; writes coalesced across t
    #pragma unroll
    for (int it = 0; it < 8; ++it) {
      const int gid = bid * 2048 + it * 256 + t;
      const int i = gid & 7, ll = (gid >> 3) & 63, ww = (gid >> 9) & 3;
      const int ql = ww*16 + (ll & 15);
      const int g = ll >> 4, c = i >> 1, rr = i & 1;
      const int kl = 16*c + 4*g + 2*rr;
      const int m0 = Ms[ql][kl], m1 = Ms[ql][kl + 1];
      pmask[gid] = (m0 ? 0xFFFFu : 0u) | (m1 ? 0xFFFF0000u : 0u);
    }
    if (blockIdx.y == 7) {
      const int idx = blockIdx.x * 256 + t;          // 0..32767
      const int k = idx >> 6, n = idx & 63;
      const float wv = Wu[(size_t)k * EMB + n];
      const unsigned short hi = f2bf(wv);
      const unsigned short lo = f2bf(wv - bf2f(hi));
      WuThi[(size_t)n * 512 + k] = hi;
      WuTlo[(size_t)n * 512 + k] = lo;
    }
    return;
  }

  const int wv_ = t >> 6, l = t & 63, g = l >> 4, q15 = l & 15;
  const int rowblk = blockIdx.x;   // 0..127
  const int h = blockIdx.y;        // 0..7
  const int b = rowblk >> 5, bh = b * HEADS + h;
  const int trow0 = rowblk * 64 + wv_ * 16;         // wave's 16 t-rows (global)
  const int tloc0 = (rowblk & 31) * 64 + wv_ * 16;  // within-batch
  const f32x4 z4 = (f32x4){0.f,0.f,0.f,0.f};

  const unsigned short* __restrict__ Ahi = (z == 2) ? yhi : xhi;
  const unsigned short* __restrict__ Alo = (z == 2) ? ylo : xlo;
  const unsigned short* __restrict__ WTz = WT + (size_t)z * 65536;

  short8 xh[2], xl[2];
  #pragma unroll
  for (int kt = 0; kt < 2; ++kt) {
    xh[kt] = *(const short8*)&Ahi[(size_t)(trow0 + q15)*64 + kt*32 + g*8];
    xl[kt] = *(const short8*)&Alo[(size_t)(trow0 + q15)*64 + kt*32 + g*8];
  }

  if (z != 1) {
    // K/Q: D[trow0+4g+r][16nt+q15] (outproj recipe, hi*hi + hi*lo + lo*hi)
    f32x4 acc[4];
    #pragma unroll
    for (int nt = 0; nt < 4; ++nt) {
      acc[nt] = z4;
      #pragma unroll
      for (int kt = 0; kt < 2; ++kt) {
        const short8 bh_ = *(const short8*)&WTz[(size_t)(h*64 + nt*16 + q15)*64 + kt*32 + g*8];
        const short8 bl_ = *(const short8*)&WTz[32768 + (size_t)(h*64 + nt*16 + q15)*64 + kt*32 + g*8];
        acc[nt] = __builtin_amdgcn_mfma_f32_16x16x32_bf16(xh[kt], bh_, acc[nt], 0,0,0);
        acc[nt] = __builtin_amdgcn_mfma_f32_16x16x32_bf16(xh[kt], bl_, acc[nt], 0,0,0);
        acc[nt] = __builtin_amdgcn_mfma_f32_16x16x32_bf16(xl[kt], bh_, acc[nt], 0,0,0);
      }
    }
    const float scale = (z == 2) ? 0.125f : 1.0f;
    unsigned short* __restrict__ dst = (z == 0) ? Kbuf : Qbuf;
    #pragma unroll
    for (int nt = 0; nt < 4; ++nt)
      #pragma unroll
      for (int r = 0; r < 4; ++r)
        dst[((size_t)bh*SEQ + tloc0 + 4*g + r)*64 + nt*16 + q15] = f2bf(acc[nt][r] * scale);
  } else {
    // V^T: D[feat = 16mt+4g+r][t = tloc0+q15] (swapped operands)
    f32x4 acc[4];
    #pragma unroll
    for (int mt = 0; mt < 4; ++mt) {
      acc[mt] = z4;
      #pragma unroll
      for (int kt = 0; kt < 2; ++kt) {
        const short8 ah_ = *(const short8*)&WTz[(size_t)(h*64 + mt*16 + q15)*64 + kt*32 + g*8];
        const short8 al_ = *(const short8*)&WTz[32768 + (size_t)(h*64 + mt*16 + q15)*64 + kt*32 + g*8];
        acc[mt] = __builtin_amdgcn_mfma_f32_16x16x32_bf16(ah_, xh[kt], acc[mt], 0,0,0);
        acc[mt] = __builtin_amdgcn_mfma_f32_16x16x32_bf16(al_, xh[kt], acc[mt], 0,0,0);
        acc[mt] = __builtin_amdgcn_mfma_f32_16x16x32_bf16(ah_, xl[kt], acc[mt], 0,0,0);
      }
    }
    #pragma unroll
    for (int mt = 0; mt < 4; ++mt)
      #pragma unroll
      for (int r = 0; r < 4; ++r)
        VbufT[((size_t)bh*EMB + mt*16 + 4*g + r)*SEQ + tloc0 + q15] = f2bf(acc[mt][r]);
  }
}

// ---- flash: R11-proven verbatim (single barrier, early STAGE, mask prefetch, setprio) ----
__global__ __launch_bounds__(256, 4) void flash_kernel(
    const unsigned short* __restrict__ Qbuf, const unsigned short* __restrict__ Kbuf,
    const unsigned short* __restrict__ VbufT, const u32* __restrict__ Pmask,
    unsigned short* __restrict__ Oint)
{
  __shared__ alignas(16) char smem[40960];
  char* const K0 = smem;
  char* const K1 = smem + 8192;
  char* const V0 = smem + 16384;
  char* const V1 = smem + 24576;

  const int t = threadIdx.x;
  const int w = t >> 6, l = t & 63, g = l >> 4, q = l & 15;
  const int id = blockIdx.x;
  const int k_ = id >> 3;
  const int bh = (id & 7) * 4 + (k_ >> 5);   // XCD-aware: per-XCD K/V L2-resident
  const int qblk = k_ & 31;
  const int b = bh >> 3, h = bh & 7;

  short8 qf[2];
  {
    const unsigned short* qp = Qbuf + ((size_t)bh*SEQ + qblk*64 + w*16 + q)*EMB + g*8;
    qf[0] = *(const short8*)qp;
    qf[1] = *(const short8*)(qp + 32);
  }

  f32x4 oacc[4];
  #pragma unroll
  for (int c = 0; c < 4; ++c) oacc[c] = (f32x4){0.f,0.f,0.f,0.f};
  const f32x4 z4 = (f32x4){0.f,0.f,0.f,0.f};
  float lsum = 0.f;

  char* const Pw = smem + 32768 + w*2048;    // wave-private P: 16 rows x 128B
  const int sw = (q & 7) << 4;

  const u32* mp = Pmask + ((size_t)(qblk*128 + w))*512 + l*8;

  const int unit0 = w*64 + l, unit1 = 256 + w*64 + l;
  const int row0 = unit0 >> 3, row1 = unit1 >> 3;
  const int gs0 = (unit0 & 7) ^ (row0 & 7), gs1 = (unit1 & 7) ^ (row1 & 7);
  const unsigned short* kp0 = Kbuf + ((size_t)bh*SEQ + row0)*EMB + gs0*8;
  const unsigned short* kp1 = Kbuf + ((size_t)bh*SEQ + row1)*EMB + gs1*8;
  const unsigned short* vp0 = VbufT + ((size_t)bh*EMB + row0)*SEQ + gs0*8;
  const unsigned short* vp1 = VbufT + ((size_t)bh*EMB + row1)*SEQ + gs1*8;

  #define STAGE(KDST, VDST) do {                                                      \
    gload16(kp0, (KDST) + (w*64)*16);                                                 \
    gload16(vp0, (VDST) + (w*64)*16);                                                 \
    gload16(kp1, (KDST) + (256 + w*64)*16);                                           \
    gload16(vp1, (VDST) + (256 + w*64)*16);                                           \
    kp0 += 64*EMB; kp1 += 64*EMB; vp0 += 64; vp1 += 64;                               \
  } while (0)

  STAGE(K0, V0);
  __syncthreads();

  uint4 mw0 = *(const uint4*)mp;
  uint4 mw1 = *(const uint4*)(mp + 4);
  mp += 2048;

  #define TILE(kbase, vbase, DOSTAGE, nkdst, nvdst) do {                               \
    f32x4 sacc[4];                                                                     \
    __builtin_amdgcn_s_setprio(1);                                                     \
    _Pragma("unroll") for (int c = 0; c < 4; ++c) {                                    \
      const short8 kf0 = *(const short8*)((kbase) + (16*c + q)*128 + ((g<<4) ^ sw));   \
      const short8 kf1 = *(const short8*)((kbase) + (16*c + q)*128 + (((4+g)<<4) ^ sw));\
      sacc[c] = __builtin_amdgcn_mfma_f32_16x16x32_bf16(kf0, qf[0], z4, 0,0,0);        \
      sacc[c] = __builtin_amdgcn_mfma_f32_16x16x32_bf16(kf1, qf[1], sacc[c], 0,0,0);   \
    }                                                                                  \
    __builtin_amdgcn_s_setprio(0);                                                     \
    if (DOSTAGE) { STAGE(nkdst, nvdst); }   /* early: hides under softmax+PV */        \
    uint4 mn0 = mw0, mn1 = mw1;                                                        \
    if (DOSTAGE) { mn0 = *(const uint4*)mp; mn1 = *(const uint4*)(mp + 4); mp += 2048; } \
    u32 pw[8];                                                                         \
    _Pragma("unroll") for (int c = 0; c < 4; ++c) {                                    \
      const float p0 = vexp2(fmaf(sacc[c][0], LOG2E, NC0));                            \
      const float p1 = vexp2(fmaf(sacc[c][1], LOG2E, NC0));                            \
      const float p2 = vexp2(fmaf(sacc[c][2], LOG2E, NC0));                            \
      const float p3 = vexp2(fmaf(sacc[c][3], LOG2E, NC0));                            \
      pw[2*c]   = cvtpk(p0, p1);                                                       \
      pw[2*c+1] = cvtpk(p2, p3);                                                       \
    }                                                                                  \
    pw[0] &= mw0.x; pw[1] &= mw0.y; pw[2] &= mw0.z; pw[3] &= mw0.w;                    \
    pw[4] &= mw1.x; pw[5] &= mw1.y; pw[6] &= mw1.z; pw[7] &= mw1.w;                    \
    _Pragma("unroll") for (int c = 0; c < 4; ++c)                                      \
      *(uint2*)(Pw + ((q*128 + 32*c + 8*g) ^ sw)) = make_uint2(pw[2*c], pw[2*c+1]);    \
    float ts = 0.f;                                                                    \
    _Pragma("unroll") for (int i = 0; i < 8; ++i)                                      \
      ts += bits2f(pw[i] << 16) + bits2f(pw[i] & 0xFFFF0000u);                         \
    ts += __shfl_xor(ts, 16);                                                          \
    ts += __shfl_xor(ts, 32);                                                          \
    lsum += ts;                                                                        \
    __builtin_amdgcn_sched_barrier(0);  /* pf reads must not hoist above P writes */   \
    short8 pf[2];                                                                      \
    pf[0] = *(const short8*)(Pw + ((q*128 + 16*g) ^ sw));                              \
    pf[1] = *(const short8*)(Pw + ((q*128 + 64 + 16*g) ^ sw));                         \
    __builtin_amdgcn_s_setprio(1);                                                     \
    _Pragma("unroll") for (int c = 0; c < 4; ++c) {                                    \
      const short8 vf0 = *(const short8*)((vbase) + (16*c + q)*128 + ((g<<4) ^ sw));   \
      const short8 vf1 = *(const short8*)((vbase) + (16*c + q)*128 + (((4+g)<<4) ^ sw));\
      oacc[c] = __builtin_amdgcn_mfma_f32_16x16x32_bf16(pf[0], vf0, oacc[c], 0,0,0);   \
      oacc[c] = __builtin_amdgcn_mfma_f32_16x16x32_bf16(pf[1], vf1, oacc[c], 0,0,0);   \
    }                                                                                  \
    __builtin_amdgcn_s_setprio(0);                                                     \
    mw0 = mn0; mw1 = mn1;                                                              \
    __syncthreads();  /* single barrier: drains staged loads; separates K/V reuse */   \
  } while (0)

  #pragma unroll 1
  for (int kt2 = 0; kt2 < 16; ++kt2) {
    TILE(K0, V0, true,       K1, V1);
    TILE(K1, V1, (kt2 < 15), K0, V0);
  }
  #undef TILE
  #undef STAGE

  #pragma unroll
  for (int r = 0; r < 4; ++r) {
    const float lr = __shfl(lsum, (l & 48) | (4*g + r));
    const float inv = (lr > 1e-30f) ? 1.f / lr : 0.f;
    #pragma unroll
    for (int c = 0; c < 4; ++c) {
      Oint[((size_t)b*SEQ + qblk*64 + w*16 + 4*g + r)*(EMB*HEADS) + h*EMB + q + 16*c] =
          f2bf(oacc[c][r] * inv);
    }
  }
}

// ---- output projection via MFMA: out = Oint(bf16) @ (WuThi + WuTlo) + bu ----
__global__ __launch_bounds__(128) void outproj_kernel(
    const unsigned short* __restrict__ Oint, const unsigned short* __restrict__ WuThi,
    const unsigned short* __restrict__ WuTlo, const float* __restrict__ bu,
    float* __restrict__ out)
{
  const int t = threadIdx.x;
  const int w = t >> 6, l = t & 63, g = l >> 4, q15 = l & 15;
  const int t0 = (blockIdx.x * 2 + w) * 16;    // 256 blocks x 2 waves -> rows 0..8191
  const f32x4 z4 = (f32x4){0.f,0.f,0.f,0.f};
  f32x4 acc[4] = {z4, z4, z4, z4};

  #pragma unroll 2
  for (int kt = 0; kt < 16; ++kt) {
    const short8 af = *(const short8*)&Oint[(size_t)(t0 + q15)*512 + kt*32 + g*8];
    #pragma unroll
    for (int nt = 0; nt < 4; ++nt) {
      const short8 bh_ = *(const short8*)&WuThi[(size_t)(nt*16 + q15)*512 + kt*32 + g*8];
      const short8 bl_ = *(const short8*)&WuTlo[(size_t)(nt*16 + q15)*512 + kt*32 + g*8];
      acc[nt] = __builtin_amdgcn_mfma_f32_16x16x32_bf16(af, bh_, acc[nt], 0,0,0);
      acc[nt] = __builtin_amdgcn_mfma_f32_16x16x32_bf16(af, bl_, acc[nt], 0,0,0);
    }
  }

  #pragma unroll
  for (int nt = 0; nt < 4; ++nt) {
    const float bv = bu[nt*16 + q15];
    #pragma unroll
    for (int r = 0; r < 4; ++r)
      out[(size_t)(t0 + 4*g + r)*EMB + nt*16 + q15] = acc[nt][r] + bv;
  }
}

extern "C" void kernel_launch(void* const* d_in, const int* in_sizes, int n_in,
                              void* d_out, int out_size, void* d_ws, size_t ws_size,
                              hipStream_t stream) {
  const float* x   = (const float*)d_in[0];
  const float* y   = (const float*)d_in[1];
  const int*   mask= (const int*)d_in[2];
  const float* Wk  = (const float*)d_in[3];
  const float* Wq  = (const float*)d_in[4];
  const float* Wv  = (const float*)d_in[5];
  const float* Wu  = (const float*)d_in[6];
  const float* bu  = (const float*)d_in[7];
  float* out = (float*)d_out;

  // ws: Qbuf(8M)|Kbuf(8M)|VbufT(8M)|Pmask(8M)|Oint(8M)|WuT(128K)|x/y hi+lo(4M)|WT(384K)
  unsigned short* Qbuf  = (unsigned short*)d_ws;
  unsigned short* Kbuf  = Qbuf + (size_t)32*SEQ*EMB;
  unsigned short* VbufT = Kbuf + (size_t)32*SEQ*EMB;
  u32* Pmask = (u32*)((char*)d_ws + (size_t)24*1024*1024);
  unsigned short* Oint  = (unsigned short*)((char*)d_ws + (size_t)32*1024*1024);
  unsigned short* WuThi = (unsigned short*)((char*)d_ws + (size_t)40*1024*1024);
  unsigned short* WuTlo = WuThi + 32768;
  unsigned short* xhi = (unsigned short*)((char*)d_ws + (size_t)40*1024*1024 + 131072);
  unsigned short* xlo = xhi + 524288;
  unsigned short* yhi = xlo + 524288;
  unsigned short* ylo = yhi + 524288;
  unsigned short* WT  = ylo + 524288;   // [3][2][512][64] ushort = 384 KB

  split_kernel<<<1408, 256, 0, stream>>>(x, y, Wk, Wq, Wv, xhi, xlo, yhi, ylo, WT);
  projmfma_kernel<<<dim3(128, 8, 4), 256, 0, stream>>>(xhi, xlo, yhi, ylo, WT, mask, Wu,
                                                       Kbuf, Qbuf, VbufT, Pmask, WuThi, WuTlo);
  flash_kernel<<<1024, 256, 0, stream>>>(Qbuf, Kbuf, VbufT, Pmask, Oint);
  outproj_kernel<<<256, 128, 0, stream>>>(Oint, WuThi, WuTlo, bu, out);
}

// Round 14
// 91.592 us; speedup vs baseline: 1.2078x; 1.2078x over previous
//
#include <hip/hip_runtime.h>

#define EMB 64
#define HEADS 8
#define SEQ 2048

typedef short short8 __attribute__((ext_vector_type(8)));
typedef float f32x4 __attribute__((ext_vector_type(4)));
typedef unsigned int u32;

__device__ __forceinline__ float4 ld4(const float* p) { return *(const float4*)p; }
__device__ __forceinline__ unsigned short f2bf(float f) {
  union { float f; unsigned u; } x; x.f = f;
  return (unsigned short)((x.u + 0x7fffu + ((x.u >> 16) & 1u)) >> 16);
}
__device__ __forceinline__ float bf2f(unsigned short s) {
  union { unsigned u; float f; } x; x.u = ((unsigned)s) << 16;
  return x.f;
}
__device__ __forceinline__ float bits2f(u32 u) {
  union { u32 u; float f; } x; x.u = u;
  return x.f;
}
__device__ __forceinline__ u32 cvtpk(float lo, float hi) {
  u32 r;
  asm("v_cvt_pk_bf16_f32 %0, %1, %2" : "=v"(r) : "v"(lo), "v"(hi));
  return r;
}
__device__ __forceinline__ float vexp2(float x) {
  float r;
  asm("v_exp_f32 %0, %1" : "=v"(r) : "v"(x));
  return r;
}
__device__ __forceinline__ void gload16(const void* g, void* l) {
  __builtin_amdgcn_global_load_lds((const __attribute__((address_space(1))) unsigned int*)g,
                                   (__attribute__((address_space(3))) unsigned int*)l, 16, 0, 0);
}

#define LOG2E 1.4426950408889634f
#define NC0  (-5.770780163555854f)   /* -4 * log2(e) */

// ---- fused prep (3-kernel pipeline): z=0 K, z=1 V^T, z=2 Q via MFMA with in-kernel
// hi/lo split; z=3 LDS-coalesced maskpack + WuT split. ----
__global__ __launch_bounds__(256) void prep_kernel(
    const float* __restrict__ x, const float* __restrict__ y,
    const float* __restrict__ Wk, const float* __restrict__ Wq, const float* __restrict__ Wv,
    const int* __restrict__ mask, const float* __restrict__ Wu,
    unsigned short* __restrict__ Kbuf, unsigned short* __restrict__ Qbuf,
    unsigned short* __restrict__ VbufT, u32* __restrict__ pmask,
    unsigned short* __restrict__ WuThi, unsigned short* __restrict__ WuTlo)
{
  __shared__ alignas(16) char psmem[18688];   // max(W panels 18432, mask tile 17408)
  const int t = threadIdx.x;
  const int z = blockIdx.z;        // 0:K 1:V^T 2:Q 3:maskpack(+WuT)

  if (z == 3) {
    int (*Ms)[68] = (int (*)[68])psmem;       // [64][68] ints = 17408 B
    const int bid = blockIdx.x * 8 + blockIdx.y;     // 0..1023 = qblk*32 + kt
    const int qblk = bid >> 5, kt = bid & 31;
    #pragma unroll
    for (int j = 0; j < 4; ++j) {
      const int idx = t + j * 256;
      const int row = idx >> 4, col4 = (idx & 15) << 2;
      *(int4*)&Ms[row][col4] =
          *(const int4*)&mask[(size_t)(qblk*64 + row) * SEQ + kt*64 + col4];
    }
    __syncthreads();
    #pragma unroll
    for (int it = 0; it < 8; ++it) {
      const int gid = bid * 2048 + it * 256 + t;
      const int i = gid & 7, ll = (gid >> 3) & 63, ww = (gid >> 9) & 3;
      const int ql = ww*16 + (ll & 15);
      const int g = ll >> 4, c = i >> 1, rr = i & 1;
      const int kl = 16*c + 4*g + 2*rr;
      const int m0 = Ms[ql][kl], m1 = Ms[ql][kl + 1];
      pmask[gid] = (m0 ? 0xFFFFu : 0u) | (m1 ? 0xFFFF0000u : 0u);
    }
    if (blockIdx.y == 7) {
      const int idx = blockIdx.x * 256 + t;          // 0..32767
      const int k = idx >> 6, n = idx & 63;
      const float wv = Wu[(size_t)k * EMB + n];
      const unsigned short hi = f2bf(wv);
      const unsigned short lo = f2bf(wv - bf2f(hi));
      WuThi[(size_t)n * 512 + k] = hi;
      WuTlo[(size_t)n * 512 + k] = lo;
    }
    return;
  }

  const int rowblk = blockIdx.x;   // 0..127
  const int h = blockIdx.y;        // 0..7
  const float* __restrict__ W = (z == 0) ? Wk : (z == 1) ? Wv : Wq;
  const float* __restrict__ Ain = (z == 2) ? y : x;

  // --- stage W head-panel -> LDS transposed hi/lo bf16, row stride 72 ushorts (16B-aligned) ---
  unsigned short* const WhT = (unsigned short*)psmem;        // [64 n][72]
  unsigned short* const WlT = WhT + 64*72;                   // [64 n][72]
  #pragma unroll
  for (int j = 0; j < 4; ++j) {
    const int idx = t + j * 256;          // 1024 float4s over [64 k][64 n]
    const int k = idx >> 4, n4 = (idx & 15) << 2;
    const float4 wv = ld4(&W[(size_t)k * (EMB*HEADS) + h*EMB + n4]);
    #pragma unroll
    for (int d = 0; d < 4; ++d) {
      const float v = (d==0)?wv.x:(d==1)?wv.y:(d==2)?wv.z:wv.w;
      const unsigned short hi = f2bf(v);
      WhT[(n4 + d)*72 + k] = hi;
      WlT[(n4 + d)*72 + k] = f2bf(v - bf2f(hi));
    }
  }
  __syncthreads();

  const int wv_ = t >> 6, l = t & 63, g = l >> 4, q15 = l & 15;
  const int b = rowblk >> 5, bh = b * HEADS + h;
  const int trow0 = rowblk * 64 + wv_ * 16;         // wave's 16 t-rows (global)
  const int tloc0 = (rowblk & 31) * 64 + wv_ * 16;  // within-batch
  const f32x4 z4 = (f32x4){0.f,0.f,0.f,0.f};

  // --- x/y row fragments, fp32 -> exact hi/lo bf16 in-register (bit-identical to split) ---
  short8 xh[2], xl[2];
  #pragma unroll
  for (int kt = 0; kt < 2; ++kt) {
    const float* ap = &Ain[(size_t)(trow0 + q15)*64 + kt*32 + g*8];
    const float4 a0 = ld4(ap), a1 = ld4(ap + 4);
    #pragma unroll
    for (int j = 0; j < 8; ++j) {
      const float v = (j<4) ? ((j==0)?a0.x:(j==1)?a0.y:(j==2)?a0.z:a0.w)
                            : ((j==4)?a1.x:(j==5)?a1.y:(j==6)?a1.z:a1.w);
      const unsigned short hi = f2bf(v);
      xh[kt][j] = (short)hi;
      xl[kt][j] = (short)f2bf(v - bf2f(hi));
    }
  }

  if (z != 1) {
    // K/Q: D[trow0+4g+r][16nt+q15] (R12-proven recipe: hi*hi + hi*lo + lo*hi)
    f32x4 acc[4];
    #pragma unroll
    for (int nt = 0; nt < 4; ++nt) {
      acc[nt] = z4;
      #pragma unroll
      for (int kt = 0; kt < 2; ++kt) {
        const short8 bh_ = *(const short8*)&WhT[(nt*16 + q15)*72 + kt*32 + g*8];
        const short8 bl_ = *(const short8*)&WlT[(nt*16 + q15)*72 + kt*32 + g*8];
        acc[nt] = __builtin_amdgcn_mfma_f32_16x16x32_bf16(xh[kt], bh_, acc[nt], 0,0,0);
        acc[nt] = __builtin_amdgcn_mfma_f32_16x16x32_bf16(xh[kt], bl_, acc[nt], 0,0,0);
        acc[nt] = __builtin_amdgcn_mfma_f32_16x16x32_bf16(xl[kt], bh_, acc[nt], 0,0,0);
      }
    }
    const float scale = (z == 2) ? 0.125f : 1.0f;
    unsigned short* __restrict__ dst = (z == 0) ? Kbuf : Qbuf;
    #pragma unroll
    for (int nt = 0; nt < 4; ++nt)
      #pragma unroll
      for (int r = 0; r < 4; ++r)
        dst[((size_t)bh*SEQ + tloc0 + 4*g + r)*64 + nt*16 + q15] = f2bf(acc[nt][r] * scale);
  } else {
    // V^T: D[feat = 16mt+4g+r][t = tloc0+q15] (R12-proven swapped operands)
    f32x4 acc[4];
    #pragma unroll
    for (int mt = 0; mt < 4; ++mt) {
      acc[mt] = z4;
      #pragma unroll
      for (int kt = 0; kt < 2; ++kt) {
        const short8 ah_ = *(const short8*)&WhT[(mt*16 + q15)*72 + kt*32 + g*8];
        const short8 al_ = *(const short8*)&WlT[(mt*16 + q15)*72 + kt*32 + g*8];
        acc[mt] = __builtin_amdgcn_mfma_f32_16x16x32_bf16(ah_, xh[kt], acc[mt], 0,0,0);
        acc[mt] = __builtin_amdgcn_mfma_f32_16x16x32_bf16(al_, xh[kt], acc[mt], 0,0,0);
        acc[mt] = __builtin_amdgcn_mfma_f32_16x16x32_bf16(ah_, xl[kt], acc[mt], 0,0,0);
      }
    }
    #pragma unroll
    for (int mt = 0; mt < 4; ++mt)
      #pragma unroll
      for (int r = 0; r < 4; ++r)
        VbufT[((size_t)bh*EMB + mt*16 + 4*g + r)*SEQ + tloc0 + q15] = f2bf(acc[mt][r]);
  }
}

// ---- flash: R11/R13-proven verbatim (single barrier, early STAGE, mask prefetch, setprio) ----
__global__ __launch_bounds__(256, 4) void flash_kernel(
    const unsigned short* __restrict__ Qbuf, const unsigned short* __restrict__ Kbuf,
    const unsigned short* __restrict__ VbufT, const u32* __restrict__ Pmask,
    unsigned short* __restrict__ Oint)
{
  __shared__ alignas(16) char smem[40960];
  char* const K0 = smem;
  char* const K1 = smem + 8192;
  char* const V0 = smem + 16384;
  char* const V1 = smem + 24576;

  const int t = threadIdx.x;
  const int w = t >> 6, l = t & 63, g = l >> 4, q = l & 15;
  const int id = blockIdx.x;
  const int k_ = id >> 3;
  const int bh = (id & 7) * 4 + (k_ >> 5);   // XCD-aware: per-XCD K/V L2-resident
  const int qblk = k_ & 31;
  const int b = bh >> 3, h = bh & 7;

  short8 qf[2];
  {
    const unsigned short* qp = Qbuf + ((size_t)bh*SEQ + qblk*64 + w*16 + q)*EMB + g*8;
    qf[0] = *(const short8*)qp;
    qf[1] = *(const short8*)(qp + 32);
  }

  f32x4 oacc[4];
  #pragma unroll
  for (int c = 0; c < 4; ++c) oacc[c] = (f32x4){0.f,0.f,0.f,0.f};
  const f32x4 z4 = (f32x4){0.f,0.f,0.f,0.f};
  float lsum = 0.f;

  char* const Pw = smem + 32768 + w*2048;    // wave-private P: 16 rows x 128B
  const int sw = (q & 7) << 4;

  const u32* mp = Pmask + ((size_t)(qblk*128 + w))*512 + l*8;

  const int unit0 = w*64 + l, unit1 = 256 + w*64 + l;
  const int row0 = unit0 >> 3, row1 = unit1 >> 3;
  const int gs0 = (unit0 & 7) ^ (row0 & 7), gs1 = (unit1 & 7) ^ (row1 & 7);
  const unsigned short* kp0 = Kbuf + ((size_t)bh*SEQ + row0)*EMB + gs0*8;
  const unsigned short* kp1 = Kbuf + ((size_t)bh*SEQ + row1)*EMB + gs1*8;
  const unsigned short* vp0 = VbufT + ((size_t)bh*EMB + row0)*SEQ + gs0*8;
  const unsigned short* vp1 = VbufT + ((size_t)bh*EMB + row1)*SEQ + gs1*8;

  #define STAGE(KDST, VDST) do {                                                      \
    gload16(kp0, (KDST) + (w*64)*16);                                                 \
    gload16(vp0, (VDST) + (w*64)*16);                                                 \
    gload16(kp1, (KDST) + (256 + w*64)*16);                                           \
    gload16(vp1, (VDST) + (256 + w*64)*16);                                           \
    kp0 += 64*EMB; kp1 += 64*EMB; vp0 += 64; vp1 += 64;                               \
  } while (0)

  STAGE(K0, V0);
  __syncthreads();

  uint4 mw0 = *(const uint4*)mp;
  uint4 mw1 = *(const uint4*)(mp + 4);
  mp += 2048;

  #define TILE(kbase, vbase, DOSTAGE, nkdst, nvdst) do {                               \
    f32x4 sacc[4];                                                                     \
    __builtin_amdgcn_s_setprio(1);                                                     \
    _Pragma("unroll") for (int c = 0; c < 4; ++c) {                                    \
      const short8 kf0 = *(const short8*)((kbase) + (16*c + q)*128 + ((g<<4) ^ sw));   \
      const short8 kf1 = *(const short8*)((kbase) + (16*c + q)*128 + (((4+g)<<4) ^ sw));\
      sacc[c] = __builtin_amdgcn_mfma_f32_16x16x32_bf16(kf0, qf[0], z4, 0,0,0);        \
      sacc[c] = __builtin_amdgcn_mfma_f32_16x16x32_bf16(kf1, qf[1], sacc[c], 0,0,0);   \
    }                                                                                  \
    __builtin_amdgcn_s_setprio(0);                                                     \
    if (DOSTAGE) { STAGE(nkdst, nvdst); }   /* early: hides under softmax+PV */        \
    uint4 mn0 = mw0, mn1 = mw1;                                                        \
    if (DOSTAGE) { mn0 = *(const uint4*)mp; mn1 = *(const uint4*)(mp + 4); mp += 2048; } \
    u32 pw[8];                                                                         \
    _Pragma("unroll") for (int c = 0; c < 4; ++c) {                                    \
      const float p0 = vexp2(fmaf(sacc[c][0], LOG2E, NC0));                            \
      const float p1 = vexp2(fmaf(sacc[c][1], LOG2E, NC0));                            \
      const float p2 = vexp2(fmaf(sacc[c][2], LOG2E, NC0));                            \
      const float p3 = vexp2(fmaf(sacc[c][3], LOG2E, NC0));                            \
      pw[2*c]   = cvtpk(p0, p1);                                                       \
      pw[2*c+1] = cvtpk(p2, p3);                                                       \
    }                                                                                  \
    pw[0] &= mw0.x; pw[1] &= mw0.y; pw[2] &= mw0.z; pw[3] &= mw0.w;                    \
    pw[4] &= mw1.x; pw[5] &= mw1.y; pw[6] &= mw1.z; pw[7] &= mw1.w;                    \
    _Pragma("unroll") for (int c = 0; c < 4; ++c)                                      \
      *(uint2*)(Pw + ((q*128 + 32*c + 8*g) ^ sw)) = make_uint2(pw[2*c], pw[2*c+1]);    \
    float ts = 0.f;                                                                    \
    _Pragma("unroll") for (int i = 0; i < 8; ++i)                                      \
      ts += bits2f(pw[i] << 16) + bits2f(pw[i] & 0xFFFF0000u);                         \
    ts += __shfl_xor(ts, 16);                                                          \
    ts += __shfl_xor(ts, 32);                                                          \
    lsum += ts;                                                                        \
    __builtin_amdgcn_sched_barrier(0);  /* pf reads must not hoist above P writes */   \
    short8 pf[2];                                                                      \
    pf[0] = *(const short8*)(Pw + ((q*128 + 16*g) ^ sw));                              \
    pf[1] = *(const short8*)(Pw + ((q*128 + 64 + 16*g) ^ sw));                         \
    __builtin_amdgcn_s_setprio(1);                                                     \
    _Pragma("unroll") for (int c = 0; c < 4; ++c) {                                    \
      const short8 vf0 = *(const short8*)((vbase) + (16*c + q)*128 + ((g<<4) ^ sw));   \
      const short8 vf1 = *(const short8*)((vbase) + (16*c + q)*128 + (((4+g)<<4) ^ sw));\
      oacc[c] = __builtin_amdgcn_mfma_f32_16x16x32_bf16(pf[0], vf0, oacc[c], 0,0,0);   \
      oacc[c] = __builtin_amdgcn_mfma_f32_16x16x32_bf16(pf[1], vf1, oacc[c], 0,0,0);   \
    }                                                                                  \
    __builtin_amdgcn_s_setprio(0);                                                     \
    mw0 = mn0; mw1 = mn1;                                                              \
    __syncthreads();  /* single barrier: drains staged loads; separates K/V reuse */   \
  } while (0)

  #pragma unroll 1
  for (int kt2 = 0; kt2 < 16; ++kt2) {
    TILE(K0, V0, true,       K1, V1);
    TILE(K1, V1, (kt2 < 15), K0, V0);
  }
  #undef TILE
  #undef STAGE

  #pragma unroll
  for (int r = 0; r < 4; ++r) {
    const float lr = __shfl(lsum, (l & 48) | (4*g + r));
    const float inv = (lr > 1e-30f) ? 1.f / lr : 0.f;
    #pragma unroll
    for (int c = 0; c < 4; ++c) {
      Oint[((size_t)b*SEQ + qblk*64 + w*16 + 4*g + r)*(EMB*HEADS) + h*EMB + q + 16*c] =
          f2bf(oacc[c][r] * inv);
    }
  }
}

// ---- output projection via MFMA: out = Oint(bf16) @ (WuThi + WuTlo) + bu ----
__global__ __launch_bounds__(128) void outproj_kernel(
    const unsigned short* __restrict__ Oint, const unsigned short* __restrict__ WuThi,
    const unsigned short* __restrict__ WuTlo, const float* __restrict__ bu,
    float* __restrict__ out)
{
  const int t = threadIdx.x;
  const int w = t >> 6, l = t & 63, g = l >> 4, q15 = l & 15;
  const int t0 = (blockIdx.x * 2 + w) * 16;    // 256 blocks x 2 waves -> rows 0..8191
  const f32x4 z4 = (f32x4){0.f,0.f,0.f,0.f};
  f32x4 acc[4] = {z4, z4, z4, z4};

  #pragma unroll 2
  for (int kt = 0; kt < 16; ++kt) {
    const short8 af = *(const short8*)&Oint[(size_t)(t0 + q15)*512 + kt*32 + g*8];
    #pragma unroll
    for (int nt = 0; nt < 4; ++nt) {
      const short8 bh_ = *(const short8*)&WuThi[(size_t)(nt*16 + q15)*512 + kt*32 + g*8];
      const short8 bl_ = *(const short8*)&WuTlo[(size_t)(nt*16 + q15)*512 + kt*32 + g*8];
      acc[nt] = __builtin_amdgcn_mfma_f32_16x16x32_bf16(af, bh_, acc[nt], 0,0,0);
      acc[nt] = __builtin_amdgcn_mfma_f32_16x16x32_bf16(af, bl_, acc[nt], 0,0,0);
    }
  }

  #pragma unroll
  for (int nt = 0; nt < 4; ++nt) {
    const float bv = bu[nt*16 + q15];
    #pragma unroll
    for (int r = 0; r < 4; ++r)
      out[(size_t)(t0 + 4*g + r)*EMB + nt*16 + q15] = acc[nt][r] + bv;
  }
}

extern "C" void kernel_launch(void* const* d_in, const int* in_sizes, int n_in,
                              void* d_out, int out_size, void* d_ws, size_t ws_size,
                              hipStream_t stream) {
  const float* x   = (const float*)d_in[0];
  const float* y   = (const float*)d_in[1];
  const int*   mask= (const int*)d_in[2];
  const float* Wk  = (const float*)d_in[3];
  const float* Wq  = (const float*)d_in[4];
  const float* Wv  = (const float*)d_in[5];
  const float* Wu  = (const float*)d_in[6];
  const float* bu  = (const float*)d_in[7];
  float* out = (float*)d_out;

  // ws: Qbuf(8M)|Kbuf(8M)|VbufT(8M)|Pmask(8M)|Oint(8M)|WuThi(64K)|WuTlo(64K)
  unsigned short* Qbuf  = (unsigned short*)d_ws;
  unsigned short* Kbuf  = Qbuf + (size_t)32*SEQ*EMB;
  unsigned short* VbufT = Kbuf + (size_t)32*SEQ*EMB;
  u32* Pmask = (u32*)((char*)d_ws + (size_t)24*1024*1024);
  unsigned short* Oint  = (unsigned short*)((char*)d_ws + (size_t)32*1024*1024);
  unsigned short* WuThi = (unsigned short*)((char*)d_ws + (size_t)40*1024*1024);
  unsigned short* WuTlo = WuThi + 32768;

  prep_kernel<<<dim3(128, 8, 4), 256, 0, stream>>>(x, y, Wk, Wq, Wv, mask, Wu,
                                                   Kbuf, Qbuf, VbufT, Pmask, WuThi, WuTlo);
  flash_kernel<<<1024, 256, 0, stream>>>(Qbuf, Kbuf, VbufT, Pmask, Oint);
  outproj_kernel<<<256, 128, 0, stream>>>(Oint, WuThi, WuTlo, bu, out);
}

// Round 15
// 85.119 us; speedup vs baseline: 1.2997x; 1.0761x over previous
//
#include <hip/hip_runtime.h>

#define EMB 64
#define HEADS 8
#define SEQ 2048

typedef short short8 __attribute__((ext_vector_type(8)));
typedef float f32x4 __attribute__((ext_vector_type(4)));
typedef unsigned int u32;

__device__ __forceinline__ float4 ld4(const float* p) { return *(const float4*)p; }
__device__ __forceinline__ unsigned short f2bf(float f) {
  union { float f; unsigned u; } x; x.f = f;
  return (unsigned short)((x.u + 0x7fffu + ((x.u >> 16) & 1u)) >> 16);
}
__device__ __forceinline__ float bf2f(unsigned short s) {
  union { unsigned u; float f; } x; x.u = ((unsigned)s) << 16;
  return x.f;
}
__device__ __forceinline__ float bits2f(u32 u) {
  union { u32 u; float f; } x; x.u = u;
  return x.f;
}
__device__ __forceinline__ u32 cvtpk(float lo, float hi) {
  u32 r;
  asm("v_cvt_pk_bf16_f32 %0, %1, %2" : "=v"(r) : "v"(lo), "v"(hi));
  return r;
}
__device__ __forceinline__ float vexp2(float x) {
  float r;
  asm("v_exp_f32 %0, %1" : "=v"(r) : "v"(x));
  return r;
}
__device__ __forceinline__ void gload16(const void* g, void* l) {
  __builtin_amdgcn_global_load_lds((const __attribute__((address_space(1))) unsigned int*)g,
                                   (__attribute__((address_space(3))) unsigned int*)l, 16, 0, 0);
}

#define LOG2E 1.4426950408889634f
#define NC0  (-5.770780163555854f)   /* -4 * log2(e) */

// ---- fused prep (R14-proven verbatim): z=0 K, z=1 V^T, z=2 Q via MFMA with in-kernel
// hi/lo split; z=3 LDS-coalesced maskpack + WuT split. ----
__global__ __launch_bounds__(256) void prep_kernel(
    const float* __restrict__ x, const float* __restrict__ y,
    const float* __restrict__ Wk, const float* __restrict__ Wq, const float* __restrict__ Wv,
    const int* __restrict__ mask, const float* __restrict__ Wu,
    unsigned short* __restrict__ Kbuf, unsigned short* __restrict__ Qbuf,
    unsigned short* __restrict__ VbufT, u32* __restrict__ pmask,
    unsigned short* __restrict__ WuThi, unsigned short* __restrict__ WuTlo)
{
  __shared__ alignas(16) char psmem[18688];
  const int t = threadIdx.x;
  const int z = blockIdx.z;

  if (z == 3) {
    int (*Ms)[68] = (int (*)[68])psmem;
    const int bid = blockIdx.x * 8 + blockIdx.y;     // 0..1023 = qblk*32 + kt
    const int qblk = bid >> 5, kt = bid & 31;
    #pragma unroll
    for (int j = 0; j < 4; ++j) {
      const int idx = t + j * 256;
      const int row = idx >> 4, col4 = (idx & 15) << 2;
      *(int4*)&Ms[row][col4] =
          *(const int4*)&mask[(size_t)(qblk*64 + row) * SEQ + kt*64 + col4];
    }
    __syncthreads();
    #pragma unroll
    for (int it = 0; it < 8; ++it) {
      const int gid = bid * 2048 + it * 256 + t;
      const int i = gid & 7, ll = (gid >> 3) & 63, ww = (gid >> 9) & 3;
      const int ql = ww*16 + (ll & 15);
      const int g = ll >> 4, c = i >> 1, rr = i & 1;
      const int kl = 16*c + 4*g + 2*rr;
      const int m0 = Ms[ql][kl], m1 = Ms[ql][kl + 1];
      pmask[gid] = (m0 ? 0xFFFFu : 0u) | (m1 ? 0xFFFF0000u : 0u);
    }
    if (blockIdx.y == 7) {
      const int idx = blockIdx.x * 256 + t;
      const int k = idx >> 6, n = idx & 63;
      const float wv = Wu[(size_t)k * EMB + n];
      const unsigned short hi = f2bf(wv);
      const unsigned short lo = f2bf(wv - bf2f(hi));
      WuThi[(size_t)n * 512 + k] = hi;
      WuTlo[(size_t)n * 512 + k] = lo;
    }
    return;
  }

  const int rowblk = blockIdx.x;
  const int h = blockIdx.y;
  const float* __restrict__ W = (z == 0) ? Wk : (z == 1) ? Wv : Wq;
  const float* __restrict__ Ain = (z == 2) ? y : x;

  unsigned short* const WhT = (unsigned short*)psmem;        // [64 n][72]
  unsigned short* const WlT = WhT + 64*72;
  #pragma unroll
  for (int j = 0; j < 4; ++j) {
    const int idx = t + j * 256;
    const int k = idx >> 4, n4 = (idx & 15) << 2;
    const float4 wv = ld4(&W[(size_t)k * (EMB*HEADS) + h*EMB + n4]);
    #pragma unroll
    for (int d = 0; d < 4; ++d) {
      const float v = (d==0)?wv.x:(d==1)?wv.y:(d==2)?wv.z:wv.w;
      const unsigned short hi = f2bf(v);
      WhT[(n4 + d)*72 + k] = hi;
      WlT[(n4 + d)*72 + k] = f2bf(v - bf2f(hi));
    }
  }
  __syncthreads();

  const int wv_ = t >> 6, l = t & 63, g = l >> 4, q15 = l & 15;
  const int b = rowblk >> 5, bh = b * HEADS + h;
  const int trow0 = rowblk * 64 + wv_ * 16;
  const int tloc0 = (rowblk & 31) * 64 + wv_ * 16;
  const f32x4 z4 = (f32x4){0.f,0.f,0.f,0.f};

  short8 xh[2], xl[2];
  #pragma unroll
  for (int kt = 0; kt < 2; ++kt) {
    const float* ap = &Ain[(size_t)(trow0 + q15)*64 + kt*32 + g*8];
    const float4 a0 = ld4(ap), a1 = ld4(ap + 4);
    #pragma unroll
    for (int j = 0; j < 8; ++j) {
      const float v = (j<4) ? ((j==0)?a0.x:(j==1)?a0.y:(j==2)?a0.z:a0.w)
                            : ((j==4)?a1.x:(j==5)?a1.y:(j==6)?a1.z:a1.w);
      const unsigned short hi = f2bf(v);
      xh[kt][j] = (short)hi;
      xl[kt][j] = (short)f2bf(v - bf2f(hi));
    }
  }

  if (z != 1) {
    f32x4 acc[4];
    #pragma unroll
    for (int nt = 0; nt < 4; ++nt) {
      acc[nt] = z4;
      #pragma unroll
      for (int kt = 0; kt < 2; ++kt) {
        const short8 bh_ = *(const short8*)&WhT[(nt*16 + q15)*72 + kt*32 + g*8];
        const short8 bl_ = *(const short8*)&WlT[(nt*16 + q15)*72 + kt*32 + g*8];
        acc[nt] = __builtin_amdgcn_mfma_f32_16x16x32_bf16(xh[kt], bh_, acc[nt], 0,0,0);
        acc[nt] = __builtin_amdgcn_mfma_f32_16x16x32_bf16(xh[kt], bl_, acc[nt], 0,0,0);
        acc[nt] = __builtin_amdgcn_mfma_f32_16x16x32_bf16(xl[kt], bh_, acc[nt], 0,0,0);
      }
    }
    const float scale = (z == 2) ? 0.125f : 1.0f;
    unsigned short* __restrict__ dst = (z == 0) ? Kbuf : Qbuf;
    #pragma unroll
    for (int nt = 0; nt < 4; ++nt)
      #pragma unroll
      for (int r = 0; r < 4; ++r)
        dst[((size_t)bh*SEQ + tloc0 + 4*g + r)*64 + nt*16 + q15] = f2bf(acc[nt][r] * scale);
  } else {
    f32x4 acc[4];
    #pragma unroll
    for (int mt = 0; mt < 4; ++mt) {
      acc[mt] = z4;
      #pragma unroll
      for (int kt = 0; kt < 2; ++kt) {
        const short8 ah_ = *(const short8*)&WhT[(mt*16 + q15)*72 + kt*32 + g*8];
        const short8 al_ = *(const short8*)&WlT[(mt*16 + q15)*72 + kt*32 + g*8];
        acc[mt] = __builtin_amdgcn_mfma_f32_16x16x32_bf16(ah_, xh[kt], acc[mt], 0,0,0);
        acc[mt] = __builtin_amdgcn_mfma_f32_16x16x32_bf16(al_, xh[kt], acc[mt], 0,0,0);
        acc[mt] = __builtin_amdgcn_mfma_f32_16x16x32_bf16(ah_, xl[kt], acc[mt], 0,0,0);
      }
    }
    #pragma unroll
    for (int mt = 0; mt < 4; ++mt)
      #pragma unroll
      for (int r = 0; r < 4; ++r)
        VbufT[((size_t)bh*EMB + mt*16 + 4*g + r)*SEQ + tloc0 + q15] = f2bf(acc[mt][r]);
  }
}

// ---- flash: R14 structure + 2 independent q-subtiles per wave (A: rows w*32+q,
// B: +16). Shared kf/vf reads halve K/V LDS redundancy. Separately-named state
// (no [s] arrays). 512 blocks. Pmask layout unchanged: qblk64 = qb2*2 + (w>>1),
// slot wwA = (w&1)*2 -> mpA; mpB = mpA + 512. ----
__global__ __launch_bounds__(256, 2) void flash_kernel(
    const unsigned short* __restrict__ Qbuf, const unsigned short* __restrict__ Kbuf,
    const unsigned short* __restrict__ VbufT, const u32* __restrict__ Pmask,
    unsigned short* __restrict__ Oint)
{
  __shared__ alignas(16) char smem[49152];
  char* const K0 = smem;
  char* const K1 = smem + 8192;
  char* const V0 = smem + 16384;
  char* const V1 = smem + 24576;

  const int t = threadIdx.x;
  const int w = t >> 6, l = t & 63, g = l >> 4, q = l & 15;
  const int id = blockIdx.x;                 // 0..511
  const int k_ = id >> 3;                    // 0..63
  const int bh = (id & 7) * 4 + (k_ >> 4);   // XCD-aware: per-XCD K/V L2-resident
  const int qb2 = k_ & 15;                   // 128-row q-block
  const int b = bh >> 3, h = bh & 7;
  const int rowA = qb2*128 + w*32;           // subtile A q-row base (+q); B = +16

  short8 qfA[2], qfB[2];
  {
    const unsigned short* qpA = Qbuf + ((size_t)bh*SEQ + rowA + q)*EMB + g*8;
    qfA[0] = *(const short8*)qpA;
    qfA[1] = *(const short8*)(qpA + 32);
    const unsigned short* qpB = qpA + 16*EMB;
    qfB[0] = *(const short8*)qpB;
    qfB[1] = *(const short8*)(qpB + 32);
  }

  f32x4 oaccA[4], oaccB[4];
  #pragma unroll
  for (int c = 0; c < 4; ++c) {
    oaccA[c] = (f32x4){0.f,0.f,0.f,0.f};
    oaccB[c] = (f32x4){0.f,0.f,0.f,0.f};
  }
  const f32x4 z4 = (f32x4){0.f,0.f,0.f,0.f};
  float lsumA = 0.f, lsumB = 0.f;

  char* const PwA = smem + 32768 + w*4096;   // wave-private P: 2 x 16 rows x 128B
  char* const PwB = PwA + 2048;
  const int sw = (q & 7) << 4;

  // Pmask: word ((qblk64*32+kt)*4 + ww)*512 + l*8 + i ; A: ww=(w&1)*2, B: +1
  const int qblk64 = qb2*2 + (w >> 1);
  const u32* mp = Pmask + ((size_t)(qblk64*128 + (w & 1)*2))*512 + l*8;

  const int unit0 = w*64 + l, unit1 = 256 + w*64 + l;
  const int row0 = unit0 >> 3, row1 = unit1 >> 3;
  const int gs0 = (unit0 & 7) ^ (row0 & 7), gs1 = (unit1 & 7) ^ (row1 & 7);
  const unsigned short* kp0 = Kbuf + ((size_t)bh*SEQ + row0)*EMB + gs0*8;
  const unsigned short* kp1 = Kbuf + ((size_t)bh*SEQ + row1)*EMB + gs1*8;
  const unsigned short* vp0 = VbufT + ((size_t)bh*EMB + row0)*SEQ + gs0*8;
  const unsigned short* vp1 = VbufT + ((size_t)bh*EMB + row1)*SEQ + gs1*8;

  #define STAGE(KDST, VDST) do {                                                      \
    gload16(kp0, (KDST) + (w*64)*16);                                                 \
    gload16(vp0, (VDST) + (w*64)*16);                                                 \
    gload16(kp1, (KDST) + (256 + w*64)*16);                                           \
    gload16(vp1, (VDST) + (256 + w*64)*16);                                           \
    kp0 += 64*EMB; kp1 += 64*EMB; vp0 += 64; vp1 += 64;                               \
  } while (0)

  STAGE(K0, V0);
  __syncthreads();

  uint4 mw0 = *(const uint4*)mp;
  uint4 mw1 = *(const uint4*)(mp + 4);
  uint4 mw2 = *(const uint4*)(mp + 512);
  uint4 mw3 = *(const uint4*)(mp + 516);
  mp += 2048;

  #define TILE(kbase, vbase, DOSTAGE, nkdst, nvdst) do {                               \
    f32x4 saccA[4], saccB[4];                                                          \
    __builtin_amdgcn_s_setprio(1);                                                     \
    _Pragma("unroll") for (int c = 0; c < 4; ++c) {                                    \
      const short8 kf0 = *(const short8*)((kbase) + (16*c + q)*128 + ((g<<4) ^ sw));   \
      const short8 kf1 = *(const short8*)((kbase) + (16*c + q)*128 + (((4+g)<<4) ^ sw));\
      saccA[c] = __builtin_amdgcn_mfma_f32_16x16x32_bf16(kf0, qfA[0], z4, 0,0,0);      \
      saccA[c] = __builtin_amdgcn_mfma_f32_16x16x32_bf16(kf1, qfA[1], saccA[c], 0,0,0);\
      saccB[c] = __builtin_amdgcn_mfma_f32_16x16x32_bf16(kf0, qfB[0], z4, 0,0,0);      \
      saccB[c] = __builtin_amdgcn_mfma_f32_16x16x32_bf16(kf1, qfB[1], saccB[c], 0,0,0);\
    }                                                                                  \
    __builtin_amdgcn_s_setprio(0);                                                     \
    if (DOSTAGE) { STAGE(nkdst, nvdst); }   /* early: hides under softmax+PV */        \
    uint4 mn0 = mw0, mn1 = mw1, mn2 = mw2, mn3 = mw3;                                  \
    if (DOSTAGE) {                                                                     \
      mn0 = *(const uint4*)mp; mn1 = *(const uint4*)(mp + 4);                          \
      mn2 = *(const uint4*)(mp + 512); mn3 = *(const uint4*)(mp + 516);                \
      mp += 2048;                                                                      \
    }                                                                                  \
    u32 pwA[8], pwB[8];                                                                \
    _Pragma("unroll") for (int c = 0; c < 4; ++c) {                                    \
      const float a0 = vexp2(fmaf(saccA[c][0], LOG2E, NC0));                           \
      const float a1 = vexp2(fmaf(saccA[c][1], LOG2E, NC0));                           \
      const float a2 = vexp2(fmaf(saccA[c][2], LOG2E, NC0));                           \
      const float a3 = vexp2(fmaf(saccA[c][3], LOG2E, NC0));                           \
      pwA[2*c]   = cvtpk(a0, a1);                                                      \
      pwA[2*c+1] = cvtpk(a2, a3);                                                      \
      const float b0 = vexp2(fmaf(saccB[c][0], LOG2E, NC0));                           \
      const float b1 = vexp2(fmaf(saccB[c][1], LOG2E, NC0));                           \
      const float b2 = vexp2(fmaf(saccB[c][2], LOG2E, NC0));                           \
      const float b3 = vexp2(fmaf(saccB[c][3], LOG2E, NC0));                           \
      pwB[2*c]   = cvtpk(b0, b1);                                                      \
      pwB[2*c+1] = cvtpk(b2, b3);                                                      \
    }                                                                                  \
    pwA[0] &= mw0.x; pwA[1] &= mw0.y; pwA[2] &= mw0.z; pwA[3] &= mw0.w;                \
    pwA[4] &= mw1.x; pwA[5] &= mw1.y; pwA[6] &= mw1.z; pwA[7] &= mw1.w;                \
    pwB[0] &= mw2.x; pwB[1] &= mw2.y; pwB[2] &= mw2.z; pwB[3] &= mw2.w;                \
    pwB[4] &= mw3.x; pwB[5] &= mw3.y; pwB[6] &= mw3.z; pwB[7] &= mw3.w;                \
    _Pragma("unroll") for (int c = 0; c < 4; ++c) {                                    \
      *(uint2*)(PwA + ((q*128 + 32*c + 8*g) ^ sw)) = make_uint2(pwA[2*c], pwA[2*c+1]); \
      *(uint2*)(PwB + ((q*128 + 32*c + 8*g) ^ sw)) = make_uint2(pwB[2*c], pwB[2*c+1]); \
    }                                                                                  \
    float tsA = 0.f, tsB = 0.f;                                                        \
    _Pragma("unroll") for (int i = 0; i < 8; ++i) {                                    \
      tsA += bits2f(pwA[i] << 16) + bits2f(pwA[i] & 0xFFFF0000u);                      \
      tsB += bits2f(pwB[i] << 16) + bits2f(pwB[i] & 0xFFFF0000u);                      \
    }                                                                                  \
    tsA += __shfl_xor(tsA, 16);                                                        \
    tsA += __shfl_xor(tsA, 32);                                                        \
    tsB += __shfl_xor(tsB, 16);                                                        \
    tsB += __shfl_xor(tsB, 32);                                                        \
    lsumA += tsA;                                                                      \
    lsumB += tsB;                                                                      \
    __builtin_amdgcn_sched_barrier(0);  /* pf reads must not hoist above P writes */   \
    short8 pfA[2], pfB[2];                                                             \
    pfA[0] = *(const short8*)(PwA + ((q*128 + 16*g) ^ sw));                            \
    pfA[1] = *(const short8*)(PwA + ((q*128 + 64 + 16*g) ^ sw));                       \
    pfB[0] = *(const short8*)(PwB + ((q*128 + 16*g) ^ sw));                            \
    pfB[1] = *(const short8*)(PwB + ((q*128 + 64 + 16*g) ^ sw));                       \
    __builtin_amdgcn_s_setprio(1);                                                     \
    _Pragma("unroll") for (int c = 0; c < 4; ++c) {                                    \
      const short8 vf0 = *(const short8*)((vbase) + (16*c + q)*128 + ((g<<4) ^ sw));   \
      const short8 vf1 = *(const short8*)((vbase) + (16*c + q)*128 + (((4+g)<<4) ^ sw));\
      oaccA[c] = __builtin_amdgcn_mfma_f32_16x16x32_bf16(pfA[0], vf0, oaccA[c], 0,0,0);\
      oaccA[c] = __builtin_amdgcn_mfma_f32_16x16x32_bf16(pfA[1], vf1, oaccA[c], 0,0,0);\
      oaccB[c] = __builtin_amdgcn_mfma_f32_16x16x32_bf16(pfB[0], vf0, oaccB[c], 0,0,0);\
      oaccB[c] = __builtin_amdgcn_mfma_f32_16x16x32_bf16(pfB[1], vf1, oaccB[c], 0,0,0);\
    }                                                                                  \
    __builtin_amdgcn_s_setprio(0);                                                     \
    mw0 = mn0; mw1 = mn1; mw2 = mn2; mw3 = mn3;                                        \
    __syncthreads();  /* single barrier: drains staged loads; separates K/V reuse */   \
  } while (0)

  #pragma unroll 1
  for (int kt2 = 0; kt2 < 16; ++kt2) {
    TILE(K0, V0, true,       K1, V1);
    TILE(K1, V1, (kt2 < 15), K0, V0);
  }
  #undef TILE
  #undef STAGE

  #pragma unroll
  for (int r = 0; r < 4; ++r) {
    const float lrA = __shfl(lsumA, (l & 48) | (4*g + r));
    const float invA = (lrA > 1e-30f) ? 1.f / lrA : 0.f;
    const float lrB = __shfl(lsumB, (l & 48) | (4*g + r));
    const float invB = (lrB > 1e-30f) ? 1.f / lrB : 0.f;
    #pragma unroll
    for (int c = 0; c < 4; ++c) {
      Oint[((size_t)b*SEQ + rowA + 4*g + r)*(EMB*HEADS) + h*EMB + q + 16*c] =
          f2bf(oaccA[c][r] * invA);
      Oint[((size_t)b*SEQ + rowA + 16 + 4*g + r)*(EMB*HEADS) + h*EMB + q + 16*c] =
          f2bf(oaccB[c][r] * invB);
    }
  }
}

// ---- output projection via MFMA (R14-proven verbatim) ----
__global__ __launch_bounds__(128) void outproj_kernel(
    const unsigned short* __restrict__ Oint, const unsigned short* __restrict__ WuThi,
    const unsigned short* __restrict__ WuTlo, const float* __restrict__ bu,
    float* __restrict__ out)
{
  const int t = threadIdx.x;
  const int w = t >> 6, l = t & 63, g = l >> 4, q15 = l & 15;
  const int t0 = (blockIdx.x * 2 + w) * 16;
  const f32x4 z4 = (f32x4){0.f,0.f,0.f,0.f};
  f32x4 acc[4] = {z4, z4, z4, z4};

  #pragma unroll 2
  for (int kt = 0; kt < 16; ++kt) {
    const short8 af = *(const short8*)&Oint[(size_t)(t0 + q15)*512 + kt*32 + g*8];
    #pragma unroll
    for (int nt = 0; nt < 4; ++nt) {
      const short8 bh_ = *(const short8*)&WuThi[(size_t)(nt*16 + q15)*512 + kt*32 + g*8];
      const short8 bl_ = *(const short8*)&WuTlo[(size_t)(nt*16 + q15)*512 + kt*32 + g*8];
      acc[nt] = __builtin_amdgcn_mfma_f32_16x16x32_bf16(af, bh_, acc[nt], 0,0,0);
      acc[nt] = __builtin_amdgcn_mfma_f32_16x16x32_bf16(af, bl_, acc[nt], 0,0,0);
    }
  }

  #pragma unroll
  for (int nt = 0; nt < 4; ++nt) {
    const float bv = bu[nt*16 + q15];
    #pragma unroll
    for (int r = 0; r < 4; ++r)
      out[(size_t)(t0 + 4*g + r)*EMB + nt*16 + q15] = acc[nt][r] + bv;
  }
}

extern "C" void kernel_launch(void* const* d_in, const int* in_sizes, int n_in,
                              void* d_out, int out_size, void* d_ws, size_t ws_size,
                              hipStream_t stream) {
  const float* x   = (const float*)d_in[0];
  const float* y   = (const float*)d_in[1];
  const int*   mask= (const int*)d_in[2];
  const float* Wk  = (const float*)d_in[3];
  const float* Wq  = (const float*)d_in[4];
  const float* Wv  = (const float*)d_in[5];
  const float* Wu  = (const float*)d_in[6];
  const float* bu  = (const float*)d_in[7];
  float* out = (float*)d_out;

  // ws: Qbuf(8M)|Kbuf(8M)|VbufT(8M)|Pmask(8M)|Oint(8M)|WuThi(64K)|WuTlo(64K)
  unsigned short* Qbuf  = (unsigned short*)d_ws;
  unsigned short* Kbuf  = Qbuf + (size_t)32*SEQ*EMB;
  unsigned short* VbufT = Kbuf + (size_t)32*SEQ*EMB;
  u32* Pmask = (u32*)((char*)d_ws + (size_t)24*1024*1024);
  unsigned short* Oint  = (unsigned short*)((char*)d_ws + (size_t)32*1024*1024);
  unsigned short* WuThi = (unsigned short*)((char*)d_ws + (size_t)40*1024*1024);
  unsigned short* WuTlo = WuThi + 32768;

  prep_kernel<<<dim3(128, 8, 4), 256, 0, stream>>>(x, y, Wk, Wq, Wv, mask, Wu,
                                                   Kbuf, Qbuf, VbufT, Pmask, WuThi, WuTlo);
  flash_kernel<<<512, 256, 0, stream>>>(Qbuf, Kbuf, VbufT, Pmask, Oint);
  outproj_kernel<<<256, 128, 0, stream>>>(Oint, WuThi, WuTlo, bu, out);
}